// Round 2
// baseline (45412.161 us; speedup 1.0000x reference)
//
#include <hip/hip_runtime.h>
#include <stdint.h>

#define MDIM   1024
#define NGATE5 5120
#define TSTEPS 8192
#define NWG    64
#define NTHR   512

typedef unsigned int u32x4 __attribute__((ext_vector_type(4)));

__device__ __forceinline__ float sigmoidf_(float x) {
  return 1.f / (1.f + __expf(-x));
}
// Fast tanh: avoids OCML tanhf (~50+ inst) on the critical path. ~1e-6 abs err.
__device__ __forceinline__ float tanhf_(float x) {
  float ax = fminf(fabsf(x), 15.f);
  float e = __expf(2.f * ax);
  float t = 1.f - 2.f / (e + 1.f);
  return copysignf(t, x);
}

// R7: DPP wave64 sum (~70 cy) replaces 6-level __shfl_xor tree (~400 cy of
// chained ds_bpermute). row_shr 1/2/4/8 -> row sums in lanes 15/31/47/63;
// bcast15 (rows 1,3) -> lanes 31,63 hold pair sums; bcast31 (rows 2,3) ->
// lane 63 holds total; readlane broadcasts via SGPR.
__device__ __forceinline__ float wsum64(float x) {
  x += __int_as_float(__builtin_amdgcn_update_dpp(0, __float_as_int(x), 0x111, 0xf, 0xf, true));
  x += __int_as_float(__builtin_amdgcn_update_dpp(0, __float_as_int(x), 0x112, 0xf, 0xf, true));
  x += __int_as_float(__builtin_amdgcn_update_dpp(0, __float_as_int(x), 0x114, 0xf, 0xf, true));
  x += __int_as_float(__builtin_amdgcn_update_dpp(0, __float_as_int(x), 0x118, 0xf, 0xf, true));
  x += __int_as_float(__builtin_amdgcn_update_dpp(0, __float_as_int(x), 0x142, 0xa, 0xf, true));
  x += __int_as_float(__builtin_amdgcn_update_dpp(0, __float_as_int(x), 0x143, 0xc, 0xf, true));
  return __int_as_float(__builtin_amdgcn_readlane(__float_as_int(x), 63));
}

// R7: LDS-only barrier. __syncthreads() drains vmcnt(0) (compiler emits
// s_waitcnt vmcnt(0) lgkmcnt(0) before s_barrier) which serializes in-flight
// publishes/prefetches into the barrier. Only LDS visibility is needed here.
__device__ __forceinline__ void lds_barrier() {
  asm volatile("s_waitcnt lgkmcnt(0)" ::: "memory");
  __builtin_amdgcn_s_barrier();
}

// One 16-B LLC-coherent load (bypasses L1/L2: per-XCD L2s are not coherent).
// Single load + single waitcnt = one fabric round trip per poll round.
// (R5: per-round buffer_inv + cacheable loads 3.8x WORSE. R4: two serialized
// vmcnt(0) loads per round doubled round latency -> 2 slots per dwordx4.
// R6: halved poll traffic + packed publish = FLAT -> latency-, not
// contention-bound; this round attacks the exposed on-CU latency instead.)
__device__ __forceinline__ u32x4 load16_coherent(const unsigned long long* p) {
  u32x4 r;
  asm volatile("global_load_dwordx4 %0, %1, off sc0 sc1\n\t"
               "s_waitcnt vmcnt(0)"
               : "=&v"(r) : "v"(p) : "memory");
  return r;
}

// Packed dual-slot publish: both (value,tag) u64 halves in ONE 16-B request.
__device__ __forceinline__ void store16_coherent(unsigned long long* p,
                                                 float v0, float v1, unsigned tag) {
  u32x4 d;
  d.x = __float_as_uint(v0); d.y = tag;
  d.z = __float_as_uint(v1); d.w = tag;
  asm volatile("global_store_dwordx4 %0, %1, off sc0 sc1"
               :: "v"(p), "v"(d) : "memory");
}

__device__ __forceinline__ unsigned long long pack_slot(float v, unsigned tag) {
  return ((unsigned long long)tag << 32) | (unsigned long long)__float_as_uint(v);
}

// ---------------------------------------------------------------------------
// Prepass: xproj[t][r] = inputs[t,:]@Wx[r,:] + bx[r] + (r<4M ? bh[r] : bm[r-4M])
// ---------------------------------------------------------------------------
#define GT_K 16
__global__ __launch_bounds__(256) void xproj_gemm(
    const float* __restrict__ A, const float* __restrict__ W,
    const float* __restrict__ bx, const float* __restrict__ bh,
    const float* __restrict__ bm, float* __restrict__ C)
{
  __shared__ float As[GT_K][64 + 4];
  __shared__ float Ws[GT_K][64 + 4];
  const int tid = threadIdx.x;
  const int tx = tid & 15, ty = tid >> 4;
  const int m0 = blockIdx.x * 64;
  const int n0 = blockIdx.y * 64;
  const int lr = tid >> 2;
  const int lk = (tid & 3) * 4;

  float acc[4][4] = {};
  for (int kb = 0; kb < MDIM; kb += GT_K) {
    const float4 av = *(const float4*)(A + (size_t)(m0 + lr) * MDIM + kb + lk);
    const float4 wv = *(const float4*)(W + (size_t)(n0 + lr) * MDIM + kb + lk);
    __syncthreads();
    As[lk + 0][lr] = av.x; As[lk + 1][lr] = av.y;
    As[lk + 2][lr] = av.z; As[lk + 3][lr] = av.w;
    Ws[lk + 0][lr] = wv.x; Ws[lk + 1][lr] = wv.y;
    Ws[lk + 2][lr] = wv.z; Ws[lk + 3][lr] = wv.w;
    __syncthreads();
    #pragma unroll
    for (int kk = 0; kk < GT_K; ++kk) {
      const float4 a = *(const float4*)(&As[kk][ty * 4]);
      const float4 w = *(const float4*)(&Ws[kk][tx * 4]);
      acc[0][0] += a.x * w.x; acc[0][1] += a.x * w.y; acc[0][2] += a.x * w.z; acc[0][3] += a.x * w.w;
      acc[1][0] += a.y * w.x; acc[1][1] += a.y * w.y; acc[1][2] += a.y * w.z; acc[1][3] += a.y * w.w;
      acc[2][0] += a.z * w.x; acc[2][1] += a.z * w.y; acc[2][2] += a.z * w.z; acc[2][3] += a.z * w.w;
      acc[3][0] += a.w * w.x; acc[3][1] += a.w * w.y; acc[3][2] += a.w * w.z; acc[3][3] += a.w * w.w;
    }
  }
  const int rbase = n0 + tx * 4;
  float bias[4];
  #pragma unroll
  for (int q = 0; q < 4; ++q) {
    const int r = rbase + q;
    bias[q] = bx[r] + (r < 4 * MDIM ? bh[r] : bm[r - 4 * MDIM]);
  }
  #pragma unroll
  for (int i = 0; i < 4; ++i) {
    const int row = m0 + ty * 4 + i;
    float4 o;
    o.x = acc[i][0] + bias[0]; o.y = acc[i][1] + bias[1];
    o.z = acc[i][2] + bias[2]; o.w = acc[i][3] + bias[3];
    *(float4*)(C + (size_t)row * NGATE5 + rbase) = o;
  }
}

// ---------------------------------------------------------------------------
// Recurrence R7: 64 WGs x 512 threads (8 waves). Wave w owns columns
// j0=wg*16+2w, j0+1. Critical-path surgery vs R6 (which proved
// latency-bound, not contention-bound):
//  - z-gate + Wm rows in LDS (64+64 KB) -> exposed z/u dots read LDS, not
//    scratch/L2 (R6's "register" weights were silently rematerialized:
//    VGPR_Count=88 despite 96-float arrays).
//  - i/o/f rows stream from L2 via explicit coalesced loads INSIDE the
//    v-wait overlap window (latency-tolerant).
//  - DPP reductions (~70cy) replace ds_bpermute shuffle trees (~400cy).
//  - xproj prefetched one step ahead: HBM latency off the poll path.
//  - hbuf/vbuf barriers are lgkmcnt-only (no vmcnt drain).
// ---------------------------------------------------------------------------
__global__ __launch_bounds__(NTHR, 2) void ulstm_persistent_p(
    const float* __restrict__ Wh, const float* __restrict__ Wm,
    const float* __restrict__ xproj, float* __restrict__ out,
    unsigned long long* __restrict__ hslot, unsigned long long* __restrict__ vslot)
{
  __shared__ alignas(16) float sWz[16][MDIM];   // z-gate rows for 16 cols, 64 KB
  __shared__ alignas(16) float sWm[16][MDIM];   // Wm rows for 16 cols,     64 KB
  __shared__ alignas(16) float hbuf[MDIM];
  __shared__ alignas(16) float vbuf[MDIM];

  const int tid  = threadIdx.x;
  const int wg   = blockIdx.x;
  const int wave = tid >> 6;
  const int lane = tid & 63;
  const int j0   = wg * 16 + wave * 2;     // owned columns j0, j0+1
  const int sb   = tid * 2;                // 2 slots per thread (one dwordx4)

  // ---- one-time staging: z rows + Wm rows -> LDS ----
  for (int idx = tid; idx < 16 * 256; idx += NTHR) {
    const int r = idx >> 8, k4 = (idx & 255) * 4;
    *(float4*)(&sWz[r][k4]) =
        *(const float4*)(Wh + (size_t)(2 * MDIM + wg * 16 + r) * MDIM + k4);
    *(float4*)(&sWm[r][k4]) =
        *(const float4*)(Wm + (size_t)(wg * 16 + r) * MDIM + k4);
  }
  __syncthreads();

  float c0 = 0.f, c1 = 0.f, tc0 = 0.f, tc1 = 0.f, h0 = 0.f, h1 = 0.f;

  // xproj for t=0 (prologue); thereafter prefetched one step ahead.
  float2 xi, xo, xz, xf, xu;
  {
    const float* xp = xproj + j0;
    xi = *(const float2*)(xp + 0 * MDIM);
    xo = *(const float2*)(xp + 1 * MDIM);
    xz = *(const float2*)(xp + 2 * MDIM);
    xf = *(const float2*)(xp + 3 * MDIM);
    xu = *(const float2*)(xp + 4 * MDIM);
  }

  for (int t = 0; t < TSTEPS; ++t) {
    // ---- wait for h(t-1): tag==t (memset gives tag0/val0 = h(-1)=0) ----
    {
      u32x4 a;
      for (;;) {
        a = load16_coherent(hslot + sb);
        if (a.y == (unsigned)t && a.w == (unsigned)t) break;
      }
      hbuf[sb + 0] = __uint_as_float(a.x);
      hbuf[sb + 1] = __uint_as_float(a.z);
    }
    lds_barrier();  // S2 (LDS-only: no vmcnt drain)

    // ---- prefetch xproj(t+1): ~2500cy of slack before its use ----
    const float* xpn = xproj + (size_t)(t + 1 < TSTEPS ? t + 1 : t) * NGATE5 + j0;
    const float2 nxi = *(const float2*)(xpn + 0 * MDIM);
    const float2 nxo = *(const float2*)(xpn + 1 * MDIM);
    const float2 nxz = *(const float2*)(xpn + 2 * MDIM);
    const float2 nxf = *(const float2*)(xpn + 3 * MDIM);
    const float2 nxu = *(const float2*)(xpn + 4 * MDIM);

    // ---- z-dots (critical path, LDS weights), packed v publish ----
    float zd0 = 0.f, zd1 = 0.f;
    #pragma unroll
    for (int i = 0; i < 4; ++i) {
      const int kb = i * 256 + lane * 4;
      const float4 hv = *(const float4*)(hbuf + kb);
      const float4 w0 = *(const float4*)(&sWz[wave * 2 + 0][kb]);
      const float4 w1 = *(const float4*)(&sWz[wave * 2 + 1][kb]);
      zd0 += w0.x*hv.x + w0.y*hv.y + w0.z*hv.z + w0.w*hv.w;
      zd1 += w1.x*hv.x + w1.y*hv.y + w1.z*hv.z + w1.w*hv.w;
    }
    zd0 = wsum64(zd0);
    zd1 = wsum64(zd1);
    const float vj0 = sigmoidf_(xz.x + zd0) * tc0;
    const float vj1 = sigmoidf_(xz.y + zd1) * tc1;
    if (lane == 0) store16_coherent(vslot + j0, vj0, vj1, (unsigned)(t + 1));

    // ---- i,o,f dots: weights stream from L2, hidden under the v-wait ----
    float id0 = 0.f, od0 = 0.f, fd0 = 0.f, id1 = 0.f, od1 = 0.f, fd1 = 0.f;
    #pragma unroll
    for (int i = 0; i < 4; ++i) {
      const int kb = i * 256 + lane * 4;
      const float4 hv  = *(const float4*)(hbuf + kb);
      const float4 wi0 = *(const float4*)(Wh + ((size_t)0 * MDIM + j0    ) * MDIM + kb);
      const float4 wi1 = *(const float4*)(Wh + ((size_t)0 * MDIM + j0 + 1) * MDIM + kb);
      const float4 wo0 = *(const float4*)(Wh + ((size_t)1 * MDIM + j0    ) * MDIM + kb);
      const float4 wo1 = *(const float4*)(Wh + ((size_t)1 * MDIM + j0 + 1) * MDIM + kb);
      const float4 wf0 = *(const float4*)(Wh + ((size_t)3 * MDIM + j0    ) * MDIM + kb);
      const float4 wf1 = *(const float4*)(Wh + ((size_t)3 * MDIM + j0 + 1) * MDIM + kb);
      id0 += wi0.x*hv.x + wi0.y*hv.y + wi0.z*hv.z + wi0.w*hv.w;
      id1 += wi1.x*hv.x + wi1.y*hv.y + wi1.z*hv.z + wi1.w*hv.w;
      od0 += wo0.x*hv.x + wo0.y*hv.y + wo0.z*hv.z + wo0.w*hv.w;
      od1 += wo1.x*hv.x + wo1.y*hv.y + wo1.z*hv.z + wo1.w*hv.w;
      fd0 += wf0.x*hv.x + wf0.y*hv.y + wf0.z*hv.z + wf0.w*hv.w;
      fd1 += wf1.x*hv.x + wf1.y*hv.y + wf1.z*hv.z + wf1.w*hv.w;
    }
    id0 = wsum64(id0); id1 = wsum64(id1);
    od0 = wsum64(od0); od1 = wsum64(od1);
    fd0 = wsum64(fd0); fd1 = wsum64(fd1);
    const float ig0 = sigmoidf_(xi.x + id0), ig1 = sigmoidf_(xi.y + id1);
    const float og0 = sigmoidf_(xo.x + od0), og1 = sigmoidf_(xo.y + od1);
    const float fc0 = sigmoidf_(xf.x + fd0) * c0;
    const float fc1 = sigmoidf_(xf.y + fd1) * c1;

    // ---- wait for v(t): tag==t+1 ----
    {
      u32x4 a;
      for (;;) {
        a = load16_coherent(vslot + sb);
        if (a.y == (unsigned)(t + 1) && a.w == (unsigned)(t + 1)) break;
      }
      vbuf[sb + 0] = __uint_as_float(a.x);
      vbuf[sb + 1] = __uint_as_float(a.z);
    }
    lds_barrier();  // S3 (LDS-only)

    // ---- u-dots (critical path, LDS weights) ----
    float md0 = 0.f, md1 = 0.f;
    #pragma unroll
    for (int i = 0; i < 4; ++i) {
      const int kb = i * 256 + lane * 4;
      const float4 vv = *(const float4*)(vbuf + kb);
      const float4 m0 = *(const float4*)(&sWm[wave * 2 + 0][kb]);
      const float4 m1 = *(const float4*)(&sWm[wave * 2 + 1][kb]);
      md0 += m0.x*vv.x + m0.y*vv.y + m0.z*vv.z + m0.w*vv.w;
      md1 += m1.x*vv.x + m1.y*vv.y + m1.z*vv.z + m1.w*vv.w;
    }
    md0 = wsum64(md0);
    md1 = wsum64(md1);
    const float u0 = tanhf_(xu.x + md0);
    const float u1 = tanhf_(xu.y + md1);
    c0 = ig0 * u0 + fc0;
    c1 = ig1 * u1 + fc1;
    const float t0n = tanhf_(c0);
    const float t1n = tanhf_(c1);
    h0 = og0 * t0n;
    h1 = og1 * t1n;
    if (lane == 0) store16_coherent(hslot + j0, h0, h1, (unsigned)(t + 1));
    tc0 = t0n; tc1 = t1n;

    xi = nxi; xo = nxo; xz = nxz; xf = nxf; xu = nxu;
  }

  if (lane == 0) {
    out[j0] = c0;        out[j0 + 1] = c1;
    out[MDIM + j0] = h0; out[MDIM + j0 + 1] = h1;
  }
}

// ---------------------------------------------------------------------------
// Fallback (ws too small for xproj): 256 WGs x 256 thr, weights from cache,
// 4 slots/thread fused-wait poll.
// ---------------------------------------------------------------------------
__device__ __forceinline__ void poll4(const unsigned long long* __restrict__ slots,
                                      float* __restrict__ dst, int base, unsigned want) {
  u32x4 a, b;
  for (;;) {
    asm volatile("global_load_dwordx4 %0, %2, off sc0 sc1\n\t"
                 "global_load_dwordx4 %1, %3, off sc0 sc1\n\t"
                 "s_waitcnt vmcnt(0)"
                 : "=&v"(a), "=&v"(b)
                 : "v"(slots + base), "v"(slots + base + 2) : "memory");
    if (a.y == want && a.w == want && b.y == want && b.w == want) break;
  }
  dst[base + 0] = __uint_as_float(a.x);
  dst[base + 1] = __uint_as_float(a.z);
  dst[base + 2] = __uint_as_float(b.x);
  dst[base + 3] = __uint_as_float(b.z);
}

__global__ __launch_bounds__(256, 1) void ulstm_persistent_f(
    const float* __restrict__ inputs, const float* __restrict__ Wx,
    const float* __restrict__ bx, const float* __restrict__ Wh,
    const float* __restrict__ bh, const float* __restrict__ Wm,
    const float* __restrict__ bm, float* __restrict__ out,
    unsigned long long* __restrict__ hslot, unsigned long long* __restrict__ vslot)
{
  __shared__ alignas(16) float xbuf[MDIM];
  __shared__ alignas(16) float hbuf[MDIM];
  __shared__ alignas(16) float vbuf[MDIM];

  const int tid  = threadIdx.x;
  const int wg   = blockIdx.x;
  const int wave = tid >> 6;
  const int lane = tid & 63;
  const int j    = wg * 4 + wave;
  const int slotbase = tid * 4;

  const float bxi = bx[j],            bxo = bx[MDIM + j],
              bxz = bx[2 * MDIM + j], bxf = bx[3 * MDIM + j],
              bxu = bx[4 * MDIM + j];
  const float bhi = bh[j],            bho = bh[MDIM + j],
              bhz = bh[2 * MDIM + j], bhf = bh[3 * MDIM + j];
  const float bmj = bm[j];

  float c = 0.f, hlast = 0.f;

  for (int t = 0; t < TSTEPS; ++t) {
    {
      float4 v = ((const float4*)(inputs + (size_t)t * MDIM))[tid];
      ((float4*)xbuf)[tid] = v;
    }
    __syncthreads();

    float xd[5] = {0, 0, 0, 0, 0};
    #pragma unroll
    for (int i = 0; i < 4; ++i) {
      const int kb = i * 256 + lane * 4;
      const float4 xv = *(const float4*)(xbuf + kb);
      #pragma unroll
      for (int g = 0; g < 5; ++g) {
        const float4 w = *(const float4*)(Wx + ((size_t)(g * MDIM + j)) * MDIM + kb);
        xd[g] += w.x * xv.x + w.y * xv.y + w.z * xv.z + w.w * xv.w;
      }
    }
    #pragma unroll
    for (int off = 32; off > 0; off >>= 1)
      #pragma unroll
      for (int g = 0; g < 5; ++g) xd[g] += __shfl_xor(xd[g], off, 64);

    poll4(hslot, hbuf, slotbase, (unsigned)t);
    __syncthreads();

    float hd[4] = {0, 0, 0, 0};
    #pragma unroll
    for (int i = 0; i < 4; ++i) {
      const int kb = i * 256 + lane * 4;
      const float4 hv = *(const float4*)(hbuf + kb);
      #pragma unroll
      for (int g = 0; g < 4; ++g) {
        const float4 w = *(const float4*)(Wh + ((size_t)(g * MDIM + j)) * MDIM + kb);
        hd[g] += w.x * hv.x + w.y * hv.y + w.z * hv.z + w.w * hv.w;
      }
    }
    #pragma unroll
    for (int off = 32; off > 0; off >>= 1)
      #pragma unroll
      for (int g = 0; g < 4; ++g) hd[g] += __shfl_xor(hd[g], off, 64);

    const float ig = sigmoidf_(xd[0] + bxi + hd[0] + bhi);
    const float og = sigmoidf_(xd[1] + bxo + hd[1] + bho);
    const float zg = sigmoidf_(xd[2] + bxz + hd[2] + bhz);
    const float fg = sigmoidf_(xd[3] + bxf + hd[3] + bhf);
    const float vj = zg * tanhf_(c);
    if (lane == 0)
      __hip_atomic_store(vslot + j, pack_slot(vj, (unsigned)(t + 1)),
                         __ATOMIC_RELAXED, __HIP_MEMORY_SCOPE_AGENT);

    poll4(vslot, vbuf, slotbase, (unsigned)(t + 1));
    __syncthreads();

    float md = 0;
    #pragma unroll
    for (int i = 0; i < 4; ++i) {
      const int kb = i * 256 + lane * 4;
      const float4 vv = *(const float4*)(vbuf + kb);
      const float4 w = *(const float4*)(Wm + (size_t)j * MDIM + kb);
      md += w.x * vv.x + w.y * vv.y + w.z * vv.z + w.w * vv.w;
    }
    #pragma unroll
    for (int off = 32; off > 0; off >>= 1) md += __shfl_xor(md, off, 64);

    const float u = tanhf_(xd[4] + bxu + md + bmj);
    c = ig * u + fg * c;
    hlast = og * tanhf_(c);
    if (lane == 0)
      __hip_atomic_store(hslot + j, pack_slot(hlast, (unsigned)(t + 1)),
                         __ATOMIC_RELAXED, __HIP_MEMORY_SCOPE_AGENT);
  }

  if (lane == 0) {
    out[j] = c;
    out[MDIM + j] = hlast;
  }
}

extern "C" void kernel_launch(void* const* d_in, const int* in_sizes, int n_in,
                              void* d_out, int out_size, void* d_ws, size_t ws_size,
                              hipStream_t stream) {
  const float* inputs = (const float*)d_in[0];
  const float* Wx     = (const float*)d_in[1];
  const float* bx     = (const float*)d_in[2];
  const float* Wh     = (const float*)d_in[3];
  const float* bh     = (const float*)d_in[4];
  const float* Wm     = (const float*)d_in[5];
  const float* bm     = (const float*)d_in[6];
  float* out = (float*)d_out;

  unsigned long long* hslot = (unsigned long long*)d_ws;
  unsigned long long* vslot = hslot + MDIM;
  const size_t slot_bytes = 2 * MDIM * sizeof(unsigned long long);
  const size_t xp_bytes   = (size_t)TSTEPS * NGATE5 * sizeof(float);

  hipMemsetAsync(d_ws, 0, slot_bytes, stream);

  if (ws_size >= slot_bytes + xp_bytes) {
    float* xproj = (float*)((char*)d_ws + slot_bytes);
    xproj_gemm<<<dim3(TSTEPS / 64, NGATE5 / 64), 256, 0, stream>>>(
        inputs, Wx, bx, bh, bm, xproj);
    ulstm_persistent_p<<<NWG, NTHR, 0, stream>>>(Wh, Wm, xproj, out, hslot, vslot);
  } else {
    ulstm_persistent_f<<<256, 256, 0, stream>>>(inputs, Wx, bx, Wh, bh, Wm, bm,
                                                out, hslot, vslot);
  }
}

// Round 4
// 23602.003 us; speedup vs baseline: 1.9241x; 1.9241x over previous
//
#include <hip/hip_runtime.h>
#include <stdint.h>

#define MDIM   1024
#define NGATE5 5120
#define TSTEPS 8192
#define NWG    128
#define NTHR   512

typedef unsigned int u32x4 __attribute__((ext_vector_type(4)));

__device__ __forceinline__ float sigmoidf_(float x) {
  return 1.f / (1.f + __expf(-x));
}
// Fast tanh: avoids OCML tanhf (~50+ inst) on the critical path. ~1e-6 abs err.
__device__ __forceinline__ float tanhf_(float x) {
  float ax = fminf(fabsf(x), 15.f);
  float e = __expf(2.f * ax);
  float t = 1.f - 2.f / (e + 1.f);
  return copysignf(t, x);
}

// DPP wave64 sum (~100 cy) replaces 6-level __shfl_xor tree (~400 cy of
// chained ds_bpermute). Proven correct in R7.
__device__ __forceinline__ float wsum64(float x) {
  x += __int_as_float(__builtin_amdgcn_update_dpp(0, __float_as_int(x), 0x111, 0xf, 0xf, true));
  x += __int_as_float(__builtin_amdgcn_update_dpp(0, __float_as_int(x), 0x112, 0xf, 0xf, true));
  x += __int_as_float(__builtin_amdgcn_update_dpp(0, __float_as_int(x), 0x114, 0xf, 0xf, true));
  x += __int_as_float(__builtin_amdgcn_update_dpp(0, __float_as_int(x), 0x118, 0xf, 0xf, true));
  x += __int_as_float(__builtin_amdgcn_update_dpp(0, __float_as_int(x), 0x142, 0xa, 0xf, true));
  x += __int_as_float(__builtin_amdgcn_update_dpp(0, __float_as_int(x), 0x143, 0xc, 0xf, true));
  return __int_as_float(__builtin_amdgcn_readlane(__float_as_int(x), 63));
}

// LDS-only barrier: __syncthreads() drains vmcnt(0) which would serialize
// in-flight publishes/prefetches into the barrier. Only LDS visibility needed.
__device__ __forceinline__ void lds_barrier() {
  asm volatile("s_waitcnt lgkmcnt(0)" ::: "memory");
  __builtin_amdgcn_s_barrier();
}

// ---- R9: FIXED 2-deep pipelined coherent poll ----------------------------
// R8 FAILED (absmax 0.994): vmcnt(1) only bounds the poll's own loads if
// they are the ONLY outstanding VMEM ops. They weren't: the 5 deferred
// xproj prefetch loads and the publish store (stores count toward vmcnt on
// CDNA) were in flight, so vmcnt(1) returned with BOTH poll loads still
// queued -> tag compare read an undefined register -> corrupt hbuf.
// FIX: drain vmcnt(0) once at poll entry. The drain is ~free: we spin >=1
// LLC round anyway, and waiting locally for our own publish store does not
// delay its remote visibility. After the drain, only the poll's two loads
// are outstanding and in-order retirement makes vmcnt(1) exact.
// sched_barrier(0) after each waitcnt pins the tag-compare below the wait
// (guide rule #18: hipcc hoists register-only ops past inline-asm waitcnt).
__device__ __forceinline__ u32x4 issue16_(const unsigned long long* p) {
  u32x4 r;
  asm volatile("global_load_dwordx4 %0, %1, off sc0 sc1"
               : "=&v"(r) : "v"(p) : "memory");
  return r;
}
__device__ __forceinline__ void wait_vm1_() {
  asm volatile("s_waitcnt vmcnt(1)" ::: "memory");
  __builtin_amdgcn_sched_barrier(0);
}
__device__ __forceinline__ void wait_vm0_() {
  asm volatile("s_waitcnt vmcnt(0)" ::: "memory");
  __builtin_amdgcn_sched_barrier(0);
}
__device__ __forceinline__ u32x4 poll2deep(const unsigned long long* p, unsigned want) {
  wait_vm0_();                 // drain foreign VMEM: poll loads now exclusive
  u32x4 a = issue16_(p);
  u32x4 b = issue16_(p);
  for (;;) {
    wait_vm1_();                                   // a complete (exact now)
    if (a.y == want && a.w == want) { wait_vm0_(); return a; }
    a = issue16_(p);
    wait_vm1_();                                   // b complete
    if (b.y == want && b.w == want) { wait_vm0_(); return b; }
    b = issue16_(p);
  }
}

__device__ __forceinline__ unsigned long long pack_slot(float v, unsigned tag) {
  return ((unsigned long long)tag << 32) | (unsigned long long)__float_as_uint(v);
}

// ---------------------------------------------------------------------------
// Prepass: xproj[t][r] = inputs[t,:]@Wx[r,:] + bx[r] + (r<4M ? bh[r] : bm[r-4M])
// ---------------------------------------------------------------------------
#define GT_K 16
__global__ __launch_bounds__(256) void xproj_gemm(
    const float* __restrict__ A, const float* __restrict__ W,
    const float* __restrict__ bx, const float* __restrict__ bh,
    const float* __restrict__ bm, float* __restrict__ C)
{
  __shared__ float As[GT_K][64 + 4];
  __shared__ float Ws[GT_K][64 + 4];
  const int tid = threadIdx.x;
  const int tx = tid & 15, ty = tid >> 4;
  const int m0 = blockIdx.x * 64;
  const int n0 = blockIdx.y * 64;
  const int lr = tid >> 2;
  const int lk = (tid & 3) * 4;

  float acc[4][4] = {};
  for (int kb = 0; kb < MDIM; kb += GT_K) {
    const float4 av = *(const float4*)(A + (size_t)(m0 + lr) * MDIM + kb + lk);
    const float4 wv = *(const float4*)(W + (size_t)(n0 + lr) * MDIM + kb + lk);
    __syncthreads();
    As[lk + 0][lr] = av.x; As[lk + 1][lr] = av.y;
    As[lk + 2][lr] = av.z; As[lk + 3][lr] = av.w;
    Ws[lk + 0][lr] = wv.x; Ws[lk + 1][lr] = wv.y;
    Ws[lk + 2][lr] = wv.z; Ws[lk + 3][lr] = wv.w;
    __syncthreads();
    #pragma unroll
    for (int kk = 0; kk < GT_K; ++kk) {
      const float4 a = *(const float4*)(&As[kk][ty * 4]);
      const float4 w = *(const float4*)(&Ws[kk][tx * 4]);
      acc[0][0] += a.x * w.x; acc[0][1] += a.x * w.y; acc[0][2] += a.x * w.z; acc[0][3] += a.x * w.w;
      acc[1][0] += a.y * w.x; acc[1][1] += a.y * w.y; acc[1][2] += a.y * w.z; acc[1][3] += a.y * w.w;
      acc[2][0] += a.z * w.x; acc[2][1] += a.z * w.y; acc[2][2] += a.z * w.z; acc[2][3] += a.z * w.w;
      acc[3][0] += a.w * w.x; acc[3][1] += a.w * w.y; acc[3][2] += a.w * w.z; acc[3][3] += a.w * w.w;
    }
  }
  const int rbase = n0 + tx * 4;
  float bias[4];
  #pragma unroll
  for (int q = 0; q < 4; ++q) {
    const int r = rbase + q;
    bias[q] = bx[r] + (r < 4 * MDIM ? bh[r] : bm[r - 4 * MDIM]);
  }
  #pragma unroll
  for (int i = 0; i < 4; ++i) {
    const int row = m0 + ty * 4 + i;
    float4 o;
    o.x = acc[i][0] + bias[0]; o.y = acc[i][1] + bias[1];
    o.z = acc[i][2] + bias[2]; o.w = acc[i][3] + bias[3];
    *(float4*)(C + (size_t)row * NGATE5 + rbase) = o;
  }
}

// ---------------------------------------------------------------------------
// Recurrence R9: proven R5 geometry (128 WGs x 512 thr; wave owns column
// j = wg*8+wave; Wh all 4 gate rows in LDS 128 KB; Wm 16 VGPRs/lane) +
// R7 micro-wins (DPP reduce, lgkmcnt-only barriers, xproj 1-step prefetch)
// + FIXED 2-deep pipelined poll (entry vmcnt(0) drain).
// ---------------------------------------------------------------------------
__global__ __launch_bounds__(NTHR, 2) void ulstm_persistent_p(
    const float* __restrict__ Wh, const float* __restrict__ Wm,
    const float* __restrict__ xproj, float* __restrict__ out,
    unsigned long long* __restrict__ hslot, unsigned long long* __restrict__ vslot)
{
  __shared__ alignas(16) float sWh[32][MDIM];   // [wave*4+gate][k]  128 KB
  __shared__ alignas(16) float hbuf[MDIM];
  __shared__ alignas(16) float vbuf[MDIM];

  const int tid  = threadIdx.x;
  const int wg   = blockIdx.x;
  const int wave = tid >> 6;
  const int lane = tid & 63;
  const int j    = wg * 8 + wave;          // owned column, 0..1023
  const int sb   = tid * 2;                // 2 slots per thread (one dwordx4)

  // ---- one-time weight staging: Wh -> LDS (fp32, float4) ----
  for (int idx = tid; idx < 32 * 256; idx += NTHR) {
    const int r = idx >> 8, k4 = (idx & 255) * 4;
    const int w_ = r >> 2, g = r & 3;
    *(float4*)(&sWh[r][k4]) =
        *(const float4*)(Wh + (size_t)(g * MDIM + wg * 8 + w_) * MDIM + k4);
  }
  // ---- Wm row for owned column -> registers (16 floats/lane) ----
  float wm[16];
  #pragma unroll
  for (int i = 0; i < 4; ++i) {
    const float4 v = *(const float4*)(Wm + (size_t)j * MDIM + i * 256 + lane * 4);
    wm[i * 4 + 0] = v.x; wm[i * 4 + 1] = v.y;
    wm[i * 4 + 2] = v.z; wm[i * 4 + 3] = v.w;
  }
  __syncthreads();

  float c = 0.f, hlast = 0.f, tc = 0.f;   // tc = tanh(c), maintained off-path

  // xproj for t=0 (prologue); thereafter prefetched one step ahead.
  float xw0, xw1, xw2, xw3, xw4;
  {
    const float* xp = xproj + j;
    xw0 = xp[0 * MDIM]; xw1 = xp[1 * MDIM]; xw2 = xp[2 * MDIM];
    xw3 = xp[3 * MDIM]; xw4 = xp[4 * MDIM];
  }

  for (int t = 0; t < TSTEPS; ++t) {
    // ---- wait for h(t-1): tag==t (memset gives tag0/val0 = h(-1)=0) ----
    {
      const u32x4 a = poll2deep(hslot + sb, (unsigned)t);
      hbuf[sb + 0] = __uint_as_float(a.x);
      hbuf[sb + 1] = __uint_as_float(a.z);
    }
    lds_barrier();  // S2 (LDS-only: no vmcnt drain)

    // ---- prefetch xproj(t+1): consumed at iteration end ----
    const float* xpn = xproj + (size_t)(t + 1 < TSTEPS ? t + 1 : t) * NGATE5 + j;
    const float nx0 = xpn[0 * MDIM];
    const float nx1 = xpn[1 * MDIM];
    const float nx2 = xpn[2 * MDIM];
    const float nx3 = xpn[3 * MDIM];
    const float nx4 = xpn[4 * MDIM];

    // ---- z-dot only (critical path, LDS weights), then publish v ----
    float hd2 = 0.f;
    #pragma unroll
    for (int i = 0; i < 4; ++i) {
      const int kb = i * 256 + lane * 4;
      const float4 hv = *(const float4*)(hbuf + kb);
      const float4 w2 = *(const float4*)(&sWh[wave * 4 + 2][kb]);
      hd2 += w2.x * hv.x + w2.y * hv.y + w2.z * hv.z + w2.w * hv.w;
    }
    hd2 = wsum64(hd2);
    const float zg = sigmoidf_(xw2 + hd2);
    const float vj = zg * tc;
    if (lane == 0) {
      __hip_atomic_store(vslot + j, pack_slot(vj, (unsigned)(t + 1)),
                         __ATOMIC_RELAXED, __HIP_MEMORY_SCOPE_AGENT);
    }

    // ---- i,o,f dots (LDS weights): overlap with the v-exchange ----
    float hd0 = 0.f, hd1 = 0.f, hd3 = 0.f;
    #pragma unroll
    for (int i = 0; i < 4; ++i) {
      const int kb = i * 256 + lane * 4;
      const float4 hv = *(const float4*)(hbuf + kb);
      const float4 w0 = *(const float4*)(&sWh[wave * 4 + 0][kb]);
      const float4 w1 = *(const float4*)(&sWh[wave * 4 + 1][kb]);
      const float4 w3 = *(const float4*)(&sWh[wave * 4 + 3][kb]);
      hd0 += w0.x * hv.x + w0.y * hv.y + w0.z * hv.z + w0.w * hv.w;
      hd1 += w1.x * hv.x + w1.y * hv.y + w1.z * hv.z + w1.w * hv.w;
      hd3 += w3.x * hv.x + w3.y * hv.y + w3.z * hv.z + w3.w * hv.w;
    }
    hd0 = wsum64(hd0);
    hd1 = wsum64(hd1);
    hd3 = wsum64(hd3);
    const float ig = sigmoidf_(xw0 + hd0);
    const float og = sigmoidf_(xw1 + hd1);
    const float fc = sigmoidf_(xw3 + hd3) * c;   // f*c precomputed off-path

    // ---- wait for v(t): tag==t+1 ----
    {
      const u32x4 a = poll2deep(vslot + sb, (unsigned)(t + 1));
      vbuf[sb + 0] = __uint_as_float(a.x);
      vbuf[sb + 1] = __uint_as_float(a.z);
    }
    lds_barrier();  // S3 (LDS-only)

    // ---- u-dot from registers ----
    float md = 0.f;
    #pragma unroll
    for (int i = 0; i < 4; ++i) {
      const int kb = i * 256 + lane * 4;
      const float4 vv = *(const float4*)(vbuf + kb);
      md += wm[i*4+0]*vv.x + wm[i*4+1]*vv.y + wm[i*4+2]*vv.z + wm[i*4+3]*vv.w;
    }
    md = wsum64(md);

    const float u = tanhf_(xw4 + md);
    c = ig * u + fc;
    const float tcn = tanhf_(c);
    hlast = og * tcn;
    if (lane == 0) {
      __hip_atomic_store(hslot + j, pack_slot(hlast, (unsigned)(t + 1)),
                         __ATOMIC_RELAXED, __HIP_MEMORY_SCOPE_AGENT);
    }
    tc = tcn;
    xw0 = nx0; xw1 = nx1; xw2 = nx2; xw3 = nx3; xw4 = nx4;
  }

  if (lane == 0) {
    out[j] = c;
    out[MDIM + j] = hlast;
  }
}

// ---------------------------------------------------------------------------
// Fallback (ws too small for xproj): 256 WGs x 256 thr, weights from cache,
// 4 slots/thread fused-wait poll.
// ---------------------------------------------------------------------------
__device__ __forceinline__ void poll4(const unsigned long long* __restrict__ slots,
                                      float* __restrict__ dst, int base, unsigned want) {
  u32x4 a, b;
  for (;;) {
    asm volatile("global_load_dwordx4 %0, %2, off sc0 sc1\n\t"
                 "global_load_dwordx4 %1, %3, off sc0 sc1\n\t"
                 "s_waitcnt vmcnt(0)"
                 : "=&v"(a), "=&v"(b)
                 : "v"(slots + base), "v"(slots + base + 2) : "memory");
    if (a.y == want && a.w == want && b.y == want && b.w == want) break;
  }
  dst[base + 0] = __uint_as_float(a.x);
  dst[base + 1] = __uint_as_float(a.z);
  dst[base + 2] = __uint_as_float(b.x);
  dst[base + 3] = __uint_as_float(b.z);
}

__global__ __launch_bounds__(256, 1) void ulstm_persistent_f(
    const float* __restrict__ inputs, const float* __restrict__ Wx,
    const float* __restrict__ bx, const float* __restrict__ Wh,
    const float* __restrict__ bh, const float* __restrict__ Wm,
    const float* __restrict__ bm, float* __restrict__ out,
    unsigned long long* __restrict__ hslot, unsigned long long* __restrict__ vslot)
{
  __shared__ alignas(16) float xbuf[MDIM];
  __shared__ alignas(16) float hbuf[MDIM];
  __shared__ alignas(16) float vbuf[MDIM];

  const int tid  = threadIdx.x;
  const int wg   = blockIdx.x;
  const int wave = tid >> 6;
  const int lane = tid & 63;
  const int j    = wg * 4 + wave;
  const int slotbase = tid * 4;

  const float bxi = bx[j],            bxo = bx[MDIM + j],
              bxz = bx[2 * MDIM + j], bxf = bx[3 * MDIM + j],
              bxu = bx[4 * MDIM + j];
  const float bhi = bh[j],            bho = bh[MDIM + j],
              bhz = bh[2 * MDIM + j], bhf = bh[3 * MDIM + j];
  const float bmj = bm[j];

  float c = 0.f, hlast = 0.f;

  for (int t = 0; t < TSTEPS; ++t) {
    {
      float4 v = ((const float4*)(inputs + (size_t)t * MDIM))[tid];
      ((float4*)xbuf)[tid] = v;
    }
    __syncthreads();

    float xd[5] = {0, 0, 0, 0, 0};
    #pragma unroll
    for (int i = 0; i < 4; ++i) {
      const int kb = i * 256 + lane * 4;
      const float4 xv = *(const float4*)(xbuf + kb);
      #pragma unroll
      for (int g = 0; g < 5; ++g) {
        const float4 w = *(const float4*)(Wx + ((size_t)(g * MDIM + j)) * MDIM + kb);
        xd[g] += w.x * xv.x + w.y * xv.y + w.z * xv.z + w.w * xv.w;
      }
    }
    #pragma unroll
    for (int off = 32; off > 0; off >>= 1)
      #pragma unroll
      for (int g = 0; g < 5; ++g) xd[g] += __shfl_xor(xd[g], off, 64);

    poll4(hslot, hbuf, slotbase, (unsigned)t);
    __syncthreads();

    float hd[4] = {0, 0, 0, 0};
    #pragma unroll
    for (int i = 0; i < 4; ++i) {
      const int kb = i * 256 + lane * 4;
      const float4 hv = *(const float4*)(hbuf + kb);
      #pragma unroll
      for (int g = 0; g < 4; ++g) {
        const float4 w = *(const float4*)(Wh + ((size_t)(g * MDIM + j)) * MDIM + kb);
        hd[g] += w.x * hv.x + w.y * hv.y + w.z * hv.z + w.w * hv.w;
      }
    }
    #pragma unroll
    for (int off = 32; off > 0; off >>= 1)
      #pragma unroll
      for (int g = 0; g < 4; ++g) hd[g] += __shfl_xor(hd[g], off, 64);

    const float ig = sigmoidf_(xd[0] + bxi + hd[0] + bhi);
    const float og = sigmoidf_(xd[1] + bxo + hd[1] + bho);
    const float zg = sigmoidf_(xd[2] + bxz + hd[2] + bhz);
    const float fg = sigmoidf_(xd[3] + bxf + hd[3] + bhf);
    const float vj = zg * tanhf_(c);
    if (lane == 0)
      __hip_atomic_store(vslot + j, pack_slot(vj, (unsigned)(t + 1)),
                         __ATOMIC_RELAXED, __HIP_MEMORY_SCOPE_AGENT);

    poll4(vslot, vbuf, slotbase, (unsigned)(t + 1));
    __syncthreads();

    float md = 0;
    #pragma unroll
    for (int i = 0; i < 4; ++i) {
      const int kb = i * 256 + lane * 4;
      const float4 vv = *(const float4*)(vbuf + kb);
      const float4 w = *(const float4*)(Wm + (size_t)j * MDIM + kb);
      md += w.x * vv.x + w.y * vv.y + w.z * vv.z + w.w * vv.w;
    }
    #pragma unroll
    for (int off = 32; off > 0; off >>= 1) md += __shfl_xor(md, off, 64);

    const float u = tanhf_(xd[4] + bxu + md + bmj);
    c = ig * u + fg * c;
    hlast = og * tanhf_(c);
    if (lane == 0)
      __hip_atomic_store(hslot + j, pack_slot(hlast, (unsigned)(t + 1)),
                         __ATOMIC_RELAXED, __HIP_MEMORY_SCOPE_AGENT);
  }

  if (lane == 0) {
    out[j] = c;
    out[MDIM + j] = hlast;
  }
}

extern "C" void kernel_launch(void* const* d_in, const int* in_sizes, int n_in,
                              void* d_out, int out_size, void* d_ws, size_t ws_size,
                              hipStream_t stream) {
  const float* inputs = (const float*)d_in[0];
  const float* Wx     = (const float*)d_in[1];
  const float* bx     = (const float*)d_in[2];
  const float* Wh     = (const float*)d_in[3];
  const float* bh     = (const float*)d_in[4];
  const float* Wm     = (const float*)d_in[5];
  const float* bm     = (const float*)d_in[6];
  float* out = (float*)d_out;

  unsigned long long* hslot = (unsigned long long*)d_ws;
  unsigned long long* vslot = hslot + MDIM;
  const size_t slot_bytes = 2 * MDIM * sizeof(unsigned long long);
  const size_t xp_bytes   = (size_t)TSTEPS * NGATE5 * sizeof(float);

  hipMemsetAsync(d_ws, 0, slot_bytes, stream);

  if (ws_size >= slot_bytes + xp_bytes) {
    float* xproj = (float*)((char*)d_ws + slot_bytes);
    xproj_gemm<<<dim3(TSTEPS / 64, NGATE5 / 64), 256, 0, stream>>>(
        inputs, Wx, bx, bh, bm, xproj);
    ulstm_persistent_p<<<NWG, NTHR, 0, stream>>>(Wh, Wm, xproj, out, hslot, vslot);
  } else {
    ulstm_persistent_f<<<256, 256, 0, stream>>>(inputs, Wx, bx, Wh, bh, Wm, bm,
                                                out, hslot, vslot);
  }
}